// Round 1
// baseline (182.536 us; speedup 1.0000x reference)
//
#include <hip/hip_runtime.h>

// NT-Xent loss, B=4096, D=256, N=16384, T=0.5.
// loss = mean_i( -pos_i + log(sum_{j!=i} exp(2*dot(zn_i, zn_j)) + 1e-12) )
//
// R3: 256x256 triangular tiles (2080 blocks), 8 waves, BK=32 triple-buffered LDS,
// counted vmcnt (never drain mid-loop), raw s_barrier, setprio around MFMA.
// exp2-fold: zb scaled by sqrt(2*log2(e)) so epilogue is a bare v_exp_f32.
//
// ws layout:
//   [0, 8MB)            : zb   — l2-normalized z * 1.6986436, bf16, [16384][256]
//   [8MB, 12MB)         : part — per-colblock row sums, f32, [64][16384]
//   [12MB, 12MB+16KB)   : pospart[4096]
//   [12MB+16KB, +256B)  : logpart[64]
// Every ws slot is written exactly once per launch -> no memset needed.

typedef __bf16 bf16;
typedef __bf16 bf16x4 __attribute__((ext_vector_type(4)));
typedef __bf16 bf16x8 __attribute__((ext_vector_type(8)));
typedef float  f32x4  __attribute__((ext_vector_type(4)));

#define NTOT 16384
#define DDIM 256
// sqrt(2*log2(e)) : dot of scaled vectors = 2*log2(e)*dot, so exp2(acc)=exp(2*dot)
#define KSCL 1.6986436f

__device__ __forceinline__ float dot4(float4 a, float4 b) {
    return a.x * b.x + a.y * b.y + a.z * b.z + a.w * b.w;
}

// ---------------- kernel 1: normalize rows -> bf16 (scaled), plus positive-pair sims ----------------
__global__ __launch_bounds__(256) void norm4k(const float* __restrict__ z1,
                                              const float* __restrict__ z2,
                                              const float* __restrict__ z3,
                                              const float* __restrict__ z4,
                                              bf16* __restrict__ zb,
                                              float* __restrict__ pospart) {
    const int wave = threadIdx.x >> 6;
    const int lane = threadIdx.x & 63;
    const int i    = blockIdx.x * 4 + wave; // 0..4095
    const float4* p1 = (const float4*)(z1 + (size_t)i * DDIM);
    const float4* p2 = (const float4*)(z2 + (size_t)i * DDIM);
    const float4* p3 = (const float4*)(z3 + (size_t)i * DDIM);
    const float4* p4 = (const float4*)(z4 + (size_t)i * DDIM);
    float4 a = p1[lane], b = p2[lane], c = p3[lane], d = p4[lane];
    float s11 = dot4(a, a), s22 = dot4(b, b), s33 = dot4(c, c), s44 = dot4(d, d);
    float s12 = dot4(a, b), s23 = dot4(b, c), s34 = dot4(c, d), s41 = dot4(d, a);
#pragma unroll
    for (int m = 32; m >= 1; m >>= 1) {
        s11 += __shfl_xor(s11, m, 64); s22 += __shfl_xor(s22, m, 64);
        s33 += __shfl_xor(s33, m, 64); s44 += __shfl_xor(s44, m, 64);
        s12 += __shfl_xor(s12, m, 64); s23 += __shfl_xor(s23, m, 64);
        s34 += __shfl_xor(s34, m, 64); s41 += __shfl_xor(s41, m, 64);
    }
    const float m1 = fmaxf(sqrtf(s11), 1e-12f), m2 = fmaxf(sqrtf(s22), 1e-12f);
    const float m3 = fmaxf(sqrtf(s33), 1e-12f), m4 = fmaxf(sqrtf(s44), 1e-12f);
    const float i1 = 1.0f / m1, i2 = 1.0f / m2, i3 = 1.0f / m3, i4 = 1.0f / m4;
    // scaled inverses for the bf16 store (fold 2*log2e into the Gram matrix)
    const float t1 = i1 * KSCL, t2 = i2 * KSCL, t3 = i3 * KSCL, t4 = i4 * KSCL;
    bf16x4 o;
    o.x = (bf16)(a.x * t1); o.y = (bf16)(a.y * t1); o.z = (bf16)(a.z * t1); o.w = (bf16)(a.w * t1);
    *(bf16x4*)(zb + (size_t)i * DDIM + lane * 4) = o;
    o.x = (bf16)(b.x * t2); o.y = (bf16)(b.y * t2); o.z = (bf16)(b.z * t2); o.w = (bf16)(b.w * t2);
    *(bf16x4*)(zb + (size_t)(i + 4096) * DDIM + lane * 4) = o;
    o.x = (bf16)(c.x * t3); o.y = (bf16)(c.y * t3); o.z = (bf16)(c.z * t3); o.w = (bf16)(c.w * t3);
    *(bf16x4*)(zb + (size_t)(i + 8192) * DDIM + lane * 4) = o;
    o.x = (bf16)(d.x * t4); o.y = (bf16)(d.y * t4); o.z = (bf16)(d.z * t4); o.w = (bf16)(d.w * t4);
    *(bf16x4*)(zb + (size_t)(i + 12288) * DDIM + lane * 4) = o;
    if (lane == 0)
        pospart[i] = 2.0f * (s12 * i1 * i2 + s23 * i2 * i3 + s34 * i3 * i4 + s41 * i4 * i1);
}

// ---------------- kernel 2: fused Gram-matrix exp-rowsum, upper triangle ----------------
// 256x256 tile per block (2080 blocks); 8 waves in 2x4; per-wave 128x64 output.
// K split into 8 tiles of BK=32; 3-buffer LDS pipeline, counted vmcnt, 1 barrier/tile.
// LDS row = 32 bf16 = 64B = 4 granules of 16B; granule g of row r at slot (g + (r>>1)) & 3
// -> conflict-free b128 reads per 8-lane group; inverse swizzle on global source.
__global__ __launch_bounds__(512, 2) void tilek(const bf16* __restrict__ zb,
                                                float* __restrict__ part) {
    __shared__ __attribute__((aligned(16))) char lds[3 * 32768]; // per buf: A[0,16K) B[16K,32K)
    __shared__ float rsum[4][256];
    __shared__ float csum[2][256];

    const int tid  = threadIdx.x;
    const int wave = tid >> 6;
    const int lane = tid & 63;
    const int quad = lane >> 4;
    const int l15  = lane & 15;
    const int wr   = wave >> 2;   // 0..1  (row half, 128 rows)
    const int wc   = wave & 3;    // 0..3  (col quarter, 64 cols)

    // triangular decode: k -> (brow, bcol), brow <= bcol, 64*65/2 = 2080 tiles
    const int k = blockIdx.x;
    int brow = (int)((129.0 - sqrt(16641.0 - 8.0 * (double)k)) * 0.5);
    if (brow > 63) brow = 63;
    while (brow < 63 && ((brow + 1) * 64 - ((brow + 1) * brow) / 2) <= k) ++brow;
    while (brow > 0 && (brow * 64 - (brow * (brow - 1)) / 2) > k) --brow;
    const int bcol = brow + (k - (brow * 64 - (brow * (brow - 1)) / 2));
    const bool isdiag = (brow == bcol);

    const char* gA = (const char*)zb + (size_t)brow * 256 * 512; // row stride 512B
    const char* gB = (const char*)zb + (size_t)bcol * 256 * 512;

    // staging geometry: 16 chunks of 1KB per matrix (16 rows x 64B each); wave owns 2 chunks
    const int row_in = lane >> 2;                 // row within chunk 0..15
    const int slot   = lane & 3;                  // swizzled granule slot this lane fills
    const int g      = (slot - (row_in >> 1)) & 3; // global granule to fetch
    const int cA0 = wave * 2, cA1 = wave * 2 + 1; // chunk ids 0..15
    const size_t goA0 = (size_t)(cA0 * 16 + row_in) * 512 + (size_t)(g << 4);
    const size_t goA1 = (size_t)(cA1 * 16 + row_in) * 512 + (size_t)(g << 4);

    auto STAGE = [&](int t, int bi) {
        char* lb = lds + bi * 32768;
        const size_t ko = (size_t)(t << 6); // t*64 bytes into each row
        __builtin_amdgcn_global_load_lds(
            (const __attribute__((address_space(1))) unsigned int*)(gA + goA0 + ko),
            (__attribute__((address_space(3))) unsigned int*)(lb + cA0 * 1024), 16, 0, 0);
        __builtin_amdgcn_global_load_lds(
            (const __attribute__((address_space(1))) unsigned int*)(gA + goA1 + ko),
            (__attribute__((address_space(3))) unsigned int*)(lb + cA1 * 1024), 16, 0, 0);
        __builtin_amdgcn_global_load_lds(
            (const __attribute__((address_space(1))) unsigned int*)(gB + goA0 + ko),
            (__attribute__((address_space(3))) unsigned int*)(lb + 16384 + cA0 * 1024), 16, 0, 0);
        __builtin_amdgcn_global_load_lds(
            (const __attribute__((address_space(1))) unsigned int*)(gB + goA1 + ko),
            (__attribute__((address_space(3))) unsigned int*)(lb + 16384 + cA1 * 1024), 16, 0, 0);
    };

    // per-lane ds_read byte offsets (within a buffer)
    int offA[8], offB[4];
#pragma unroll
    for (int rt = 0; rt < 8; ++rt) {
        int ar = (wr << 7) + (rt << 4) + l15;
        offA[rt] = ar * 64 + (((quad + (ar >> 1)) & 3) << 4);
    }
#pragma unroll
    for (int ct = 0; ct < 4; ++ct) {
        int br = (wc << 6) + (ct << 4) + l15;
        offB[ct] = 16384 + br * 64 + (((quad + (br >> 1)) & 3) << 4);
    }

    f32x4 zero = {0.f, 0.f, 0.f, 0.f};
    f32x4 acc[8][4];
#pragma unroll
    for (int a = 0; a < 8; ++a)
#pragma unroll
        for (int b = 0; b < 4; ++b) acc[a][b] = zero;

    STAGE(0, 0);
    STAGE(1, 1);

#pragma unroll 8
    for (int t = 0; t < 8; ++t) {
        // gate: this tile's 4 loads done; keep later tiles' loads in flight
        if (t < 7) asm volatile("s_waitcnt vmcnt(4)" ::: "memory");
        else       asm volatile("s_waitcnt vmcnt(0)" ::: "memory");
        __builtin_amdgcn_s_barrier();
        asm volatile("" ::: "memory"); // no LDS read hoists above the barrier

        if (t < 6) STAGE(t + 2, (t + 2) % 3); // issue-early; lands under MFMA

        const char* lb = lds + (t % 3) * 32768;
        bf16x8 af[8], bfr[4];
#pragma unroll
        for (int rt = 0; rt < 8; ++rt) af[rt] = *(const bf16x8*)(lb + offA[rt]);
#pragma unroll
        for (int ct = 0; ct < 4; ++ct) bfr[ct] = *(const bf16x8*)(lb + offB[ct]);

        __builtin_amdgcn_s_setprio(1);
#pragma unroll
        for (int rt = 0; rt < 8; ++rt)
#pragma unroll
            for (int ct = 0; ct < 4; ++ct)
                acc[rt][ct] = __builtin_amdgcn_mfma_f32_16x16x32_bf16(
                    af[rt], bfr[ct], acc[rt][ct], 0, 0, 0);
        __builtin_amdgcn_s_setprio(0);
    }

    // epilogue: e = exp2(acc) = exp(2*dot) (diag masked); row-sums over l15, col-sums over quad
    const int rb = wr << 7;  // tile-local row base of this wave
    const int cb = wc << 6;  // tile-local col base
    float cs[4] = {0.f, 0.f, 0.f, 0.f};
#pragma unroll
    for (int rt = 0; rt < 8; ++rt) {
        float rs[4] = {0.f, 0.f, 0.f, 0.f};
        const int rtile = rb + (rt << 4);
#pragma unroll
        for (int ct = 0; ct < 4; ++ct) {
            const int ctile = cb + (ct << 4);
#pragma unroll
            for (int r = 0; r < 4; ++r) {
                float e;
                asm("v_exp_f32 %0, %1" : "=v"(e) : "v"(acc[rt][ct][r]));
                if (isdiag && (rtile + (quad << 2) + r) == (ctile + l15)) e = 0.f; // self-sim
                rs[r] += e;
                cs[ct] += e;
            }
        }
        // row-sums: reduce across 16 lanes (C-layout: col = lane&15)
#pragma unroll
        for (int m = 1; m <= 8; m <<= 1)
#pragma unroll
            for (int r = 0; r < 4; ++r) rs[r] += __shfl_xor(rs[r], m, 64);
        if (l15 == 0) {
            int lrow = rtile + (quad << 2);
#pragma unroll
            for (int r = 0; r < 4; ++r) rsum[wc][lrow + r] = rs[r];
        }
    }
    // col-sums: reduce across the 4 quads (rows), lanes 16 apart
#pragma unroll
    for (int m = 16; m <= 32; m <<= 1)
#pragma unroll
        for (int ct = 0; ct < 4; ++ct) cs[ct] += __shfl_xor(cs[ct], m, 64);
    if (quad == 0) {
#pragma unroll
        for (int ct = 0; ct < 4; ++ct) csum[wr][cb + (ct << 4) + l15] = cs[ct];
    }
    __syncthreads();
    if (tid < 256) {
        float rv = rsum[0][tid] + rsum[1][tid] + rsum[2][tid] + rsum[3][tid];
        part[(size_t)bcol * NTOT + brow * 256 + tid] = rv;
    } else if (!isdiag) {
        int c = tid & 255;
        float cv = csum[0][c] + csum[1][c];
        part[(size_t)brow * NTOT + bcol * 256 + c] = cv;
    }
}

// ---------------- kernel 3: reduce partials per row, take log ----------------
__global__ __launch_bounds__(256) void rowlog(const float* __restrict__ part,
                                              float* __restrict__ logpart) {
    const int row = blockIdx.x * 256 + threadIdx.x;
    float s = 0.f;
#pragma unroll 8
    for (int c = 0; c < 64; ++c) s += part[(size_t)c * NTOT + row];
    float lg = logf(s + 1e-12f);
#pragma unroll
    for (int m = 32; m >= 1; m >>= 1) lg += __shfl_xor(lg, m, 64);
    __shared__ float red[4];
    const int wave = threadIdx.x >> 6, lane = threadIdx.x & 63;
    if (lane == 0) red[wave] = lg;
    __syncthreads();
    if (threadIdx.x == 0) logpart[blockIdx.x] = red[0] + red[1] + red[2] + red[3];
}

// ---------------- kernel 4: finalize ----------------
__global__ __launch_bounds__(256) void finalk(const float* __restrict__ pospart,
                                              const float* __restrict__ logpart,
                                              float* __restrict__ out) {
    const int t = threadIdx.x;
    float sp = 0.f, sl = 0.f;
    for (int k = t; k < 4096; k += 256) sp += pospart[k];
    if (t < 64) sl = logpart[t];
#pragma unroll
    for (int m = 32; m >= 1; m >>= 1) { sp += __shfl_xor(sp, m, 64); sl += __shfl_xor(sl, m, 64); }
    __shared__ float rp[4], rl[4];
    const int wave = t >> 6, lane = t & 63;
    if (lane == 0) { rp[wave] = sp; rl[wave] = sl; }
    __syncthreads();
    if (t == 0) {
        float P = rp[0] + rp[1] + rp[2] + rp[3];
        float L = rl[0] + rl[1] + rl[2] + rl[3];
        out[0] = (L - P) / 16384.0f;
    }
}

extern "C" void kernel_launch(void* const* d_in, const int* in_sizes, int n_in,
                              void* d_out, int out_size, void* d_ws, size_t ws_size,
                              hipStream_t stream) {
    const float* z1 = (const float*)d_in[0];
    const float* z2 = (const float*)d_in[1];
    const float* z3 = (const float*)d_in[2];
    const float* z4 = (const float*)d_in[3];
    float* out = (float*)d_out;

    char* ws = (char*)d_ws;
    bf16*  zb      = (bf16*)ws;                                  // 8 MB
    float* part    = (float*)(ws + (size_t)(8u << 20));          // 4 MB
    float* pospart = (float*)(ws + (size_t)(12u << 20));         // 16 KB
    float* logpart = (float*)(ws + (size_t)(12u << 20) + 16384); // 256 B

    norm4k<<<1024, 256, 0, stream>>>(z1, z2, z3, z4, zb, pospart);
    tilek<<<2080, 512, 0, stream>>>(zb, part);
    rowlog<<<64, 256, 0, stream>>>(part, logpart);
    finalk<<<1, 256, 0, stream>>>(pospart, logpart, out);
}